// Round 1
// 659.299 us; speedup vs baseline: 1.1787x; 1.1787x over previous
//
#include <hip/hip_runtime.h>
#include <math.h>

#define NN    1000000
#define DEG   64
#define BATCH 4096
#define NS    25
#define EMB   64
#define HD    128

// workspace layout (float offsets)
#define OFF_A1     0            // 128x64   A1  = w1x@prepW   (row-major [k][d])
#define OFF_A1N    8192         // 128x64   A1n = w1n@prepW
#define OFF_W2XB   16384        // 128x128  w2x[:,128:]  (row-major [k][d])
#define OFF_W2NLO  32768        // 128x128  w2n[:,:128]
#define OFF_W2NHI  49152        // 128x128  w2n[:,128:]
#define OFF_C1X    65536        // 128
#define OFF_C1N    65664        // 128
#define OFF_V0     65792        // 128
#define OFF_MH1    13538304     // 4096x256  meanH1
#define OFF_G0     14586880     // 4096x128  g0

// ---- named-register weight tile: 16 float4 = 64 weights ----
#define WDECL(P) float4 P##0,P##1,P##2,P##3,P##4,P##5,P##6,P##7,P##8,P##9,P##10,P##11,P##12,P##13,P##14,P##15;
#define WLOAD(P, SRC) { const float4* _w = (const float4*)(SRC); \
  P##0=_w[0];  P##1=_w[1];  P##2=_w[2];  P##3=_w[3]; \
  P##4=_w[4];  P##5=_w[5];  P##6=_w[6];  P##7=_w[7]; \
  P##8=_w[8];  P##9=_w[9];  P##10=_w[10];P##11=_w[11]; \
  P##12=_w[12];P##13=_w[13];P##14=_w[14];P##15=_w[15]; }
// pin: opaque asm prevents rematerialization/sinking of the weight loads
#define PIN4(Q) asm volatile("" : "+v"(Q.x), "+v"(Q.y), "+v"(Q.z), "+v"(Q.w));
#define WPIN(P) { PIN4(P##0) PIN4(P##1) PIN4(P##2) PIN4(P##3) PIN4(P##4) PIN4(P##5) \
  PIN4(P##6) PIN4(P##7) PIN4(P##8) PIN4(P##9) PIN4(P##10) PIN4(P##11) PIN4(P##12) \
  PIN4(P##13) PIN4(P##14) PIN4(P##15) }
#define FMA4(WQ, V, a0,a1,a2,a3) { a0=fmaf(WQ.x,(V).x,a0); a1=fmaf(WQ.y,(V).y,a1); \
                                   a2=fmaf(WQ.z,(V).z,a2); a3=fmaf(WQ.w,(V).w,a3); }
#define DOT64(P, XPTR, a0,a1,a2,a3) { const float4* _x=(const float4*)(XPTR); float4 _v; \
  _v=_x[0];  FMA4(P##0,_v,a0,a1,a2,a3)  _v=_x[1];  FMA4(P##1,_v,a0,a1,a2,a3) \
  _v=_x[2];  FMA4(P##2,_v,a0,a1,a2,a3)  _v=_x[3];  FMA4(P##3,_v,a0,a1,a2,a3) \
  _v=_x[4];  FMA4(P##4,_v,a0,a1,a2,a3)  _v=_x[5];  FMA4(P##5,_v,a0,a1,a2,a3) \
  _v=_x[6];  FMA4(P##6,_v,a0,a1,a2,a3)  _v=_x[7];  FMA4(P##7,_v,a0,a1,a2,a3) \
  _v=_x[8];  FMA4(P##8,_v,a0,a1,a2,a3)  _v=_x[9];  FMA4(P##9,_v,a0,a1,a2,a3) \
  _v=_x[10]; FMA4(P##10,_v,a0,a1,a2,a3) _v=_x[11]; FMA4(P##11,_v,a0,a1,a2,a3) \
  _v=_x[12]; FMA4(P##12,_v,a0,a1,a2,a3) _v=_x[13]; FMA4(P##13,_v,a0,a1,a2,a3) \
  _v=_x[14]; FMA4(P##14,_v,a0,a1,a2,a3) _v=_x[15]; FMA4(P##15,_v,a0,a1,a2,a3) }

// ---------------------------------------------------------------- K0: tiny precompute
__global__ void k0_prep(const float* __restrict__ emb, const float* __restrict__ prepW,
                        const float* __restrict__ prepb,
                        const float* __restrict__ w1x, const float* __restrict__ w1n,
                        const float* __restrict__ w2x, const float* __restrict__ w2n,
                        float* __restrict__ ws) {
  int t = threadIdx.x;
  int b = blockIdx.x;
  if (b == 0 || b == 1) {
    const float* W = (b == 0) ? w1x : w1n;
    float* A = ws + ((b == 0) ? OFF_A1 : OFF_A1N);
    float* c = ws + ((b == 0) ? OFF_C1X : OFF_C1N);
    for (int idx = t; idx < 128 * 64; idx += 256) {
      int k = idx >> 6, d = idx & 63;
      float s = 0.f;
      for (int a = 0; a < 64; ++a) s += W[k * 64 + a] * prepW[a * 64 + d];
      A[k * 64 + d] = s;
    }
    if (t < 128) {
      float s = 0.f;
      for (int a = 0; a < 64; ++a) s += W[t * 64 + a] * prepb[a];
      c[t] = s;
    }
  } else if (b == 2) {
    for (int idx = t; idx < 128 * 128; idx += 256) {
      int k = idx >> 7, d = idx & 127;
      ws[OFF_W2XB  + k * 128 + d] = w2x[k * 256 + 128 + d];
      ws[OFF_W2NLO + k * 128 + d] = w2n[k * 256 + d];
      ws[OFF_W2NHI + k * 128 + d] = w2n[k * 256 + 128 + d];
    }
  } else {
    __shared__ float e0[64], u[128];
    if (t < 64) {
      float s = prepb[t];
      for (int d = 0; d < 64; ++d) s += emb[(size_t)NN * 64 + d] * prepW[t * 64 + d];
      e0[t] = s;
    }
    __syncthreads();
    if (t < 128) {
      float s = 0.f;
      for (int a = 0; a < 64; ++a) s += w1x[t * 64 + a] * e0[a];
      u[t] = fmaxf(s, 0.f);
    }
    __syncthreads();
    if (t < 128) {
      float s = 0.f;
      for (int k = 0; k < 128; ++k) s += u[k] * w2x[t * 256 + k];
      ws[OFF_V0 + t] = s;
    }
  }
}

// ---------------------------------------------------------------- K2 fused:
// hop-1 sample + hop-2 gather + layer-1 (both pairs) + group means + g0.
// One block per batch row. Gather is float4-vectorized: each wave-load
// instruction fetches FOUR embedding rows at once (16 lanes x 16B per row),
// 4x fewer load instructions and 4x more bytes in flight per vmcnt slot
// than the previous one-row-per-load scheme. Hop-2 ids are staged in LDS
// (written and read only by the owning wave -> no barrier needed; invalid
// lanes clamp to row w which this wave already wrote, so no uninitialized
// LDS index can reach a global load).
__global__ __launch_bounds__(256, 3) void k2_fused(const int* __restrict__ ids,
                                                   const int* __restrict__ adj,
                                                   const int* __restrict__ perm1,
                                                   const int* __restrict__ perm2,
                                                   const float* __restrict__ emb,
                                                   const float* __restrict__ wsc,
                                                   float* __restrict__ ws) {
  __shared__ __align__(16) float X1t[NS][64];
  __shared__ __align__(16) float ME2t[NS][64];
  __shared__ __align__(16) float me1s[64];
  __shared__ int nb2s[NS * NS];          // [r][j] hop-2 node ids
  int t = threadIdx.x, i = blockIdx.x;
  int lane = t & 63, w = t >> 6;
  bool xp = (t < 128);
  int k = t & 127;

  // issue weight loads now; they stay in flight through the gather phase
  WDECL(W)
  WLOAD(W, wsc + (xp ? OFF_A1 : OFF_A1N) + k * 64)
  float bias = wsc[(xp ? OFF_C1X : OFF_C1N) + k];

  // hop-1: every wave loads the 25 hop-1 neighbors (redundant across waves, L1-hot)
  int root = ids[i];
  int p1 = (lane < NS) ? perm1[lane] : 0;
  int p2 = (lane < NS) ? perm2[lane] : 0;
  int nb1 = adj[(size_t)root * DEG + p1];

  // adjacency rows for my owned hop-1 rows (r = w, w+4, ...); all loads issued
  // before any LDS write so they overlap.
  int nbrow[7];
#pragma unroll
  for (int kk = 0; kk < 7; ++kk) {
    int r = w + 4 * kk;
    if (r < NS) {                        // wave-uniform predicate
      int node = __shfl(nb1, r, 64);
      nbrow[kk] = adj[(size_t)node * DEG + p2];
    }
  }
#pragma unroll
  for (int kk = 0; kk < 7; ++kk) {
    int r = w + 4 * kk;
    if (r < NS && lane < NS) nb2s[r * NS + lane] = nbrow[kk];
  }

  // ---- float4 gather: lane (g,q) handles columns q*4..q*4+3 of row (w+4*(c*4+g)) ----
  int g = lane >> 4, q = lane & 15;
#pragma unroll
  for (int c = 0; c < 2; ++c) {
    int r = w + 4 * (c * 4 + g);         // chunk0 covers rows 0..15, chunk1 rows 16..24
    bool valid = (r < NS);
    int rsafe = valid ? r : w;           // row w: owned + already written by this wave
    int nid1 = __shfl(nb1, rsafe, 64);
    float4 x1v = *((const float4*)(emb + (size_t)nid1 * EMB) + q);
    float4 acc = make_float4(0.f, 0.f, 0.f, 0.f);
#pragma unroll
    for (int j = 0; j < NS; ++j) {
      int nid = nb2s[rsafe * NS + j];    // broadcast within each 16-lane group
      float4 v = *((const float4*)(emb + (size_t)nid * EMB) + q);
      acc.x += v.x; acc.y += v.y; acc.z += v.z; acc.w += v.w;
    }
    if (valid) {
      *(float4*)&X1t[r][q * 4] = x1v;
      float4 m;
      m.x = acc.x * (1.f / NS); m.y = acc.y * (1.f / NS);
      m.z = acc.z * (1.f / NS); m.w = acc.w * (1.f / NS);
      *(float4*)&ME2t[r][q * 4] = m;
    }
  }
  __syncthreads();
  // meanE1 = column means of X1t
  if (t < 64) {
    float s = 0.f;
#pragma unroll
    for (int r = 0; r < NS; ++r) s += X1t[r][t];
    me1s[t] = s * (1.f / NS);
  }
  WPIN(W)            // materialize weights in VGPRs before the dot phase
  __syncthreads();

  float S = 0.f;
  const float* Xt = xp ? &X1t[0][0] : &ME2t[0][0];
  for (int r = 0; r < NS; ++r) {
    float a0 = bias, a1 = 0.f, a2 = 0.f, a3 = 0.f;
    DOT64(W, Xt + r * 64, a0, a1, a2, a3)
    S += fmaxf((a0 + a1) + (a2 + a3), 0.f);
  }
  ws[OFF_MH1 + (size_t)i * 256 + t] = S * (1.f / NS);
  if (!xp) {         // n-branch threads also produce g0 (h0's neighbor half)
    float a0 = bias, a1 = 0.f, a2 = 0.f, a3 = 0.f;
    DOT64(W, me1s, a0, a1, a2, a3)
    ws[OFF_G0 + (size_t)i * 128 + k] = fmaxf((a0 + a1) + (a2 + a3), 0.f);
  }
}

// ---------------------------------------------------------------- K3b: layer-2 + normalize + fc
__global__ __launch_bounds__(384, 1) void k3b_final(const float* __restrict__ wsc,
                                                    const float* __restrict__ fcW,
                                                    const float* __restrict__ fcb,
                                                    float* __restrict__ out) {
  __shared__ __align__(16) float xrow[384];   // [0:128) g0 row, [128:384) mh1 row
  __shared__ float partB[128];
  __shared__ float redN[6], redD[6];
  int t = threadIdx.x, b = blockIdx.x;
  int role = t >> 7;
  int k = t & 127;
  const float* Wrow = wsc + (role == 0 ? OFF_W2XB : (role == 1 ? OFF_W2NLO : OFF_W2NHI))
                    + k * 128;
  WDECL(W)
  WDECL(X)
  WLOAD(W, Wrow)
  WLOAD(X, Wrow + 64)
  WPIN(W)
  WPIN(X)
  float v0k = (role == 0) ? wsc[OFF_V0 + k] : 0.f;
  float fcw = (t < 256) ? fcW[t] : 0.f;
  float fcbv = fcb[0];
  for (int it = 0; it < 8; ++it) {
    int i = b * 8 + it;
    xrow[t] = (t < 128) ? wsc[OFF_G0 + (size_t)i * 128 + t]
                        : wsc[OFF_MH1 + (size_t)i * 256 + (t - 128)];
    __syncthreads();
    const float* xbase = (role == 0) ? xrow : (role == 1 ? xrow + 128 : xrow + 256);
    float a0 = v0k, a1 = 0.f, a2 = 0.f, a3 = 0.f;
    DOT64(W, xbase, a0, a1, a2, a3)
    DOT64(X, xbase + 64, a0, a1, a2, a3)
    float acc = (a0 + a1) + (a2 + a3);
    if (role == 2) partB[k] = acc;
    __syncthreads();
    float y = 0.f;
    if (role == 0)      y = acc;
    else if (role == 1) y = acc + partB[k];
    float n2 = y * y, dt = y * fcw;
#pragma unroll
    for (int off = 32; off > 0; off >>= 1) {
      n2 += __shfl_down(n2, off, 64);
      dt += __shfl_down(dt, off, 64);
    }
    int w = t >> 6;
    if ((t & 63) == 0) { redN[w] = n2; redD[w] = dt; }
    __syncthreads();
    if (t == 0) {
      float N = 0.f, D = 0.f;
#pragma unroll
      for (int ww = 0; ww < 6; ++ww) { N += redN[ww]; D += redD[ww]; }
      out[i] = D / fmaxf(sqrtf(N), 1e-12f) + fcbv;
    }
    __syncthreads();
  }
}

// ----------------------------------------------------------------
extern "C" void kernel_launch(void* const* d_in, const int* in_sizes, int n_in,
                              void* d_out, int out_size, void* d_ws, size_t ws_size,
                              hipStream_t stream) {
  const float* emb   = (const float*)d_in[0];
  const float* prepW = (const float*)d_in[1];
  const float* prepb = (const float*)d_in[2];
  const float* w1x   = (const float*)d_in[3];
  const float* w1n   = (const float*)d_in[4];
  const float* w2x   = (const float*)d_in[5];
  const float* w2n   = (const float*)d_in[6];
  const float* fcW   = (const float*)d_in[7];
  const float* fcb   = (const float*)d_in[8];
  const int* ids     = (const int*)d_in[9];
  const int* adj     = (const int*)d_in[10];
  const int* perm1   = (const int*)d_in[11];
  const int* perm2   = (const int*)d_in[12];
  float* ws  = (float*)d_ws;
  float* out = (float*)d_out;

  hipLaunchKernelGGL(k0_prep, dim3(4), dim3(256), 0, stream,
                     emb, prepW, prepb, w1x, w1n, w2x, w2n, ws);
  hipLaunchKernelGGL(k2_fused, dim3(BATCH), dim3(256), 0, stream,
                     ids, adj, perm1, perm2, emb, ws, ws);
  hipLaunchKernelGGL(k3b_final, dim3(BATCH / 8), dim3(384), 0, stream,
                     ws, fcW, fcb, out);
}

// Round 2
// 601.171 us; speedup vs baseline: 1.2927x; 1.0967x over previous
//
#include <hip/hip_runtime.h>
#include <math.h>

#define NN    1000000
#define DEG   64
#define BATCH 4096
#define NS    25
#define EMB   64
#define HD    128

// workspace layout (float offsets)
#define OFF_A1     0            // 128x64   A1  = w1x@prepW   (row-major [k][d])
#define OFF_A1N    8192         // 128x64   A1n = w1n@prepW
#define OFF_W2XB   16384        // 128x128  w2x[:,128:]  (row-major [k][d])
#define OFF_W2NLO  32768        // 128x128  w2n[:,:128]
#define OFF_W2NHI  49152        // 128x128  w2n[:,128:]
#define OFF_C1X    65536        // 128
#define OFF_C1N    65664        // 128
#define OFF_V0     65792        // 128
#define OFF_MH1    13538304     // 4096x256  meanH1
#define OFF_G0     14586880     // 4096x128  g0

// ---- named-register weight tile: 16 float4 = 64 weights ----
#define WDECL(P) float4 P##0,P##1,P##2,P##3,P##4,P##5,P##6,P##7,P##8,P##9,P##10,P##11,P##12,P##13,P##14,P##15;
#define WLOAD(P, SRC) { const float4* _w = (const float4*)(SRC); \
  P##0=_w[0];  P##1=_w[1];  P##2=_w[2];  P##3=_w[3]; \
  P##4=_w[4];  P##5=_w[5];  P##6=_w[6];  P##7=_w[7]; \
  P##8=_w[8];  P##9=_w[9];  P##10=_w[10];P##11=_w[11]; \
  P##12=_w[12];P##13=_w[13];P##14=_w[14];P##15=_w[15]; }
// pin: opaque asm prevents rematerialization/sinking of the weight loads
#define PIN4(Q) asm volatile("" : "+v"(Q.x), "+v"(Q.y), "+v"(Q.z), "+v"(Q.w));
#define WPIN(P) { PIN4(P##0) PIN4(P##1) PIN4(P##2) PIN4(P##3) PIN4(P##4) PIN4(P##5) \
  PIN4(P##6) PIN4(P##7) PIN4(P##8) PIN4(P##9) PIN4(P##10) PIN4(P##11) PIN4(P##12) \
  PIN4(P##13) PIN4(P##14) PIN4(P##15) }
#define FMA4(WQ, V, a0,a1,a2,a3) { a0=fmaf(WQ.x,(V).x,a0); a1=fmaf(WQ.y,(V).y,a1); \
                                   a2=fmaf(WQ.z,(V).z,a2); a3=fmaf(WQ.w,(V).w,a3); }
#define DOT64(P, XPTR, a0,a1,a2,a3) { const float4* _x=(const float4*)(XPTR); float4 _v; \
  _v=_x[0];  FMA4(P##0,_v,a0,a1,a2,a3)  _v=_x[1];  FMA4(P##1,_v,a0,a1,a2,a3) \
  _v=_x[2];  FMA4(P##2,_v,a0,a1,a2,a3)  _v=_x[3];  FMA4(P##3,_v,a0,a1,a2,a3) \
  _v=_x[4];  FMA4(P##4,_v,a0,a1,a2,a3)  _v=_x[5];  FMA4(P##5,_v,a0,a1,a2,a3) \
  _v=_x[6];  FMA4(P##6,_v,a0,a1,a2,a3)  _v=_x[7];  FMA4(P##7,_v,a0,a1,a2,a3) \
  _v=_x[8];  FMA4(P##8,_v,a0,a1,a2,a3)  _v=_x[9];  FMA4(P##9,_v,a0,a1,a2,a3) \
  _v=_x[10]; FMA4(P##10,_v,a0,a1,a2,a3) _v=_x[11]; FMA4(P##11,_v,a0,a1,a2,a3) \
  _v=_x[12]; FMA4(P##12,_v,a0,a1,a2,a3) _v=_x[13]; FMA4(P##13,_v,a0,a1,a2,a3) \
  _v=_x[14]; FMA4(P##14,_v,a0,a1,a2,a3) _v=_x[15]; FMA4(P##15,_v,a0,a1,a2,a3) }

// 25-wide repetition for the gather batch
#define REP25(F) F(0)F(1)F(2)F(3)F(4)F(5)F(6)F(7)F(8)F(9)F(10)F(11)F(12) \
                 F(13)F(14)F(15)F(16)F(17)F(18)F(19)F(20)F(21)F(22)F(23)F(24)
#define LDN(J)  int n_##J = nrow[J];
#define LDV(J)  float4 v_##J = *((const float4*)(emb + (size_t)n_##J * EMB) + q);
#define ACCV(J) { accx += v_##J.x; accy += v_##J.y; accz += v_##J.z; accw += v_##J.w; }

// ---------------------------------------------------------------- K0: tiny precompute
__global__ void k0_prep(const float* __restrict__ emb, const float* __restrict__ prepW,
                        const float* __restrict__ prepb,
                        const float* __restrict__ w1x, const float* __restrict__ w1n,
                        const float* __restrict__ w2x, const float* __restrict__ w2n,
                        float* __restrict__ ws) {
  int t = threadIdx.x;
  int b = blockIdx.x;
  if (b == 0 || b == 1) {
    const float* W = (b == 0) ? w1x : w1n;
    float* A = ws + ((b == 0) ? OFF_A1 : OFF_A1N);
    float* c = ws + ((b == 0) ? OFF_C1X : OFF_C1N);
    for (int idx = t; idx < 128 * 64; idx += 256) {
      int k = idx >> 6, d = idx & 63;
      float s = 0.f;
      for (int a = 0; a < 64; ++a) s += W[k * 64 + a] * prepW[a * 64 + d];
      A[k * 64 + d] = s;
    }
    if (t < 128) {
      float s = 0.f;
      for (int a = 0; a < 64; ++a) s += W[t * 64 + a] * prepb[a];
      c[t] = s;
    }
  } else if (b == 2) {
    for (int idx = t; idx < 128 * 128; idx += 256) {
      int k = idx >> 7, d = idx & 127;
      ws[OFF_W2XB  + k * 128 + d] = w2x[k * 256 + 128 + d];
      ws[OFF_W2NLO + k * 128 + d] = w2n[k * 256 + d];
      ws[OFF_W2NHI + k * 128 + d] = w2n[k * 256 + 128 + d];
    }
  } else {
    __shared__ float e0[64], u[128];
    if (t < 64) {
      float s = prepb[t];
      for (int d = 0; d < 64; ++d) s += emb[(size_t)NN * 64 + d] * prepW[t * 64 + d];
      e0[t] = s;
    }
    __syncthreads();
    if (t < 128) {
      float s = 0.f;
      for (int a = 0; a < 64; ++a) s += w1x[t * 64 + a] * e0[a];
      u[t] = fmaxf(s, 0.f);
    }
    __syncthreads();
    if (t < 128) {
      float s = 0.f;
      for (int k = 0; k < 128; ++k) s += u[k] * w2x[t * 256 + k];
      ws[OFF_V0 + t] = s;
    }
  }
}

// ---------------------------------------------------------------- K2 fused:
// hop-1 sample + hop-2 gather + layer-1 (both pairs) + group means + g0.
// One block per batch row. The gather phase runs with the FULL register
// file (weights are loaded only afterwards): each 16-lane group batches
// all 26 float4 loads (1 hop-1 row + 25 hop-2 rows) into named registers
// so ~26 loads stay in flight per wave per chunk. Invalid groups are
// exec-masked (no loads issued).
__global__ __launch_bounds__(256, 3) void k2_fused(const int* __restrict__ ids,
                                                   const int* __restrict__ adj,
                                                   const int* __restrict__ perm1,
                                                   const int* __restrict__ perm2,
                                                   const float* __restrict__ emb,
                                                   const float* __restrict__ wsc,
                                                   float* __restrict__ ws) {
  __shared__ __align__(16) float X1t[NS][64];
  __shared__ __align__(16) float ME2t[NS][64];
  __shared__ __align__(16) float me1s[64];
  __shared__ int nb2s[NS * NS];          // [r][j] hop-2 node ids
  int t = threadIdx.x, i = blockIdx.x;
  int lane = t & 63, w = t >> 6;
  bool xp = (t < 128);
  int k = t & 127;

  // hop-1: every wave loads the 25 hop-1 neighbors (redundant across waves, L1-hot)
  int root = ids[i];
  int p1 = (lane < NS) ? perm1[lane] : 0;
  int p2 = (lane < NS) ? perm2[lane] : 0;
  int nb1 = adj[(size_t)root * DEG + p1];

  // adjacency rows for my owned hop-1 rows (r = w, w+4, ...); all loads issued
  // before any LDS write so they overlap.
  int nbrow[7];
#pragma unroll
  for (int kk = 0; kk < 7; ++kk) {
    int r = w + 4 * kk;
    if (r < NS) {                        // wave-uniform predicate
      int node = __shfl(nb1, r, 64);
      nbrow[kk] = adj[(size_t)node * DEG + p2];
    }
  }
#pragma unroll
  for (int kk = 0; kk < 7; ++kk) {
    int r = w + 4 * kk;
    if (r < NS && lane < NS) nb2s[r * NS + lane] = nbrow[kk];
  }

  // ---- float4 gather: lane (g,q) handles columns q*4..q*4+3 of row (w+4*(c*4+g)).
  // All 26 loads of a chunk are issued back-to-back into named registers.
  int g = lane >> 4, q = lane & 15;
#pragma unroll
  for (int c = 0; c < 2; ++c) {
    int r = w + 4 * (c * 4 + g);         // chunk0 covers rows 0..15, chunk1 rows 16..24
    bool valid = (r < NS);
    int rclamp = valid ? r : w;
    int nid1 = __shfl(nb1, rclamp, 64);  // shfl outside the divergent region
    if (valid) {
      const int* nrow = &nb2s[r * NS];
      REP25(LDN)                         // 25 hop-2 ids (LDS, broadcast per group)
      float4 x1v = *((const float4*)(emb + (size_t)nid1 * EMB) + q);
      REP25(LDV)                         // 25 independent float4 gathers in flight
      float accx = 0.f, accy = 0.f, accz = 0.f, accw = 0.f;
      REP25(ACCV)
      *(float4*)&X1t[r][q * 4] = x1v;
      float4 m;
      m.x = accx * (1.f / NS); m.y = accy * (1.f / NS);
      m.z = accz * (1.f / NS); m.w = accw * (1.f / NS);
      *(float4*)&ME2t[r][q * 4] = m;
    }
  }

  // weights are loaded ONLY now (wsc is L2-hot) so the gather above had the
  // whole register file for its load window.
  WDECL(W)
  WLOAD(W, wsc + (xp ? OFF_A1 : OFF_A1N) + k * 64)
  float bias = wsc[(xp ? OFF_C1X : OFF_C1N) + k];

  __syncthreads();
  // meanE1 = column means of X1t
  if (t < 64) {
    float s = 0.f;
#pragma unroll
    for (int r = 0; r < NS; ++r) s += X1t[r][t];
    me1s[t] = s * (1.f / NS);
  }
  WPIN(W)            // materialize weights in VGPRs before the dot phase
  __syncthreads();

  float S = 0.f;
  const float* Xt = xp ? &X1t[0][0] : &ME2t[0][0];
  for (int r = 0; r < NS; ++r) {
    float a0 = bias, a1 = 0.f, a2 = 0.f, a3 = 0.f;
    DOT64(W, Xt + r * 64, a0, a1, a2, a3)
    S += fmaxf((a0 + a1) + (a2 + a3), 0.f);
  }
  ws[OFF_MH1 + (size_t)i * 256 + t] = S * (1.f / NS);
  if (!xp) {         // n-branch threads also produce g0 (h0's neighbor half)
    float a0 = bias, a1 = 0.f, a2 = 0.f, a3 = 0.f;
    DOT64(W, me1s, a0, a1, a2, a3)
    ws[OFF_G0 + (size_t)i * 128 + k] = fmaxf((a0 + a1) + (a2 + a3), 0.f);
  }
}

// ---------------------------------------------------------------- K3b: layer-2 + normalize + fc
__global__ __launch_bounds__(384, 1) void k3b_final(const float* __restrict__ wsc,
                                                    const float* __restrict__ fcW,
                                                    const float* __restrict__ fcb,
                                                    float* __restrict__ out) {
  __shared__ __align__(16) float xrow[384];   // [0:128) g0 row, [128:384) mh1 row
  __shared__ float partB[128];
  __shared__ float redN[6], redD[6];
  int t = threadIdx.x, b = blockIdx.x;
  int role = t >> 7;
  int k = t & 127;
  const float* Wrow = wsc + (role == 0 ? OFF_W2XB : (role == 1 ? OFF_W2NLO : OFF_W2NHI))
                    + k * 128;
  WDECL(W)
  WDECL(X)
  WLOAD(W, Wrow)
  WLOAD(X, Wrow + 64)
  WPIN(W)
  WPIN(X)
  float v0k = (role == 0) ? wsc[OFF_V0 + k] : 0.f;
  float fcw = (t < 256) ? fcW[t] : 0.f;
  float fcbv = fcb[0];
  for (int it = 0; it < 8; ++it) {
    int i = b * 8 + it;
    xrow[t] = (t < 128) ? wsc[OFF_G0 + (size_t)i * 128 + t]
                        : wsc[OFF_MH1 + (size_t)i * 256 + (t - 128)];
    __syncthreads();
    const float* xbase = (role == 0) ? xrow : (role == 1 ? xrow + 128 : xrow + 256);
    float a0 = v0k, a1 = 0.f, a2 = 0.f, a3 = 0.f;
    DOT64(W, xbase, a0, a1, a2, a3)
    DOT64(X, xbase + 64, a0, a1, a2, a3)
    float acc = (a0 + a1) + (a2 + a3);
    if (role == 2) partB[k] = acc;
    __syncthreads();
    float y = 0.f;
    if (role == 0)      y = acc;
    else if (role == 1) y = acc + partB[k];
    float n2 = y * y, dt = y * fcw;
#pragma unroll
    for (int off = 32; off > 0; off >>= 1) {
      n2 += __shfl_down(n2, off, 64);
      dt += __shfl_down(dt, off, 64);
    }
    int w = t >> 6;
    if ((t & 63) == 0) { redN[w] = n2; redD[w] = dt; }
    __syncthreads();
    if (t == 0) {
      float N = 0.f, D = 0.f;
#pragma unroll
      for (int ww = 0; ww < 6; ++ww) { N += redN[ww]; D += redD[ww]; }
      out[i] = D / fmaxf(sqrtf(N), 1e-12f) + fcbv;
    }
    __syncthreads();
  }
}

// ----------------------------------------------------------------
extern "C" void kernel_launch(void* const* d_in, const int* in_sizes, int n_in,
                              void* d_out, int out_size, void* d_ws, size_t ws_size,
                              hipStream_t stream) {
  const float* emb   = (const float*)d_in[0];
  const float* prepW = (const float*)d_in[1];
  const float* prepb = (const float*)d_in[2];
  const float* w1x   = (const float*)d_in[3];
  const float* w1n   = (const float*)d_in[4];
  const float* w2x   = (const float*)d_in[5];
  const float* w2n   = (const float*)d_in[6];
  const float* fcW   = (const float*)d_in[7];
  const float* fcb   = (const float*)d_in[8];
  const int* ids     = (const int*)d_in[9];
  const int* adj     = (const int*)d_in[10];
  const int* perm1   = (const int*)d_in[11];
  const int* perm2   = (const int*)d_in[12];
  float* ws  = (float*)d_ws;
  float* out = (float*)d_out;

  hipLaunchKernelGGL(k0_prep, dim3(4), dim3(256), 0, stream,
                     emb, prepW, prepb, w1x, w1n, w2x, w2n, ws);
  hipLaunchKernelGGL(k2_fused, dim3(BATCH), dim3(256), 0, stream,
                     ids, adj, perm1, perm2, emb, ws, ws);
  hipLaunchKernelGGL(k3b_final, dim3(BATCH / 8), dim3(384), 0, stream,
                     ws, fcW, fcb, out);
}